// Round 5
// baseline (925.378 us; speedup 1.0000x reference)
//
#include <hip/hip_runtime.h>
#include <math.h>

#define CDIM 256
#define NPIX 4096
#define BATCH 4
#define QB 64
#define KB 32
#define KVHALF 2048

typedef __attribute__((ext_vector_type(8))) short short8;
typedef __attribute__((ext_vector_type(4))) float f32x4;
#define MFMA(a, b, c) __builtin_amdgcn_mfma_f32_16x16x32_bf16((a), (b), (c), 0, 0, 0)

__device__ __forceinline__ unsigned short f2bf(float f) {
    union { float f; unsigned int u; } v; v.f = f;
    unsigned int u = v.u;
    return (unsigned short)((u + 0x7FFFu + ((u >> 16) & 1u)) >> 16);
}
__device__ __forceinline__ float bf2f(unsigned short h) {
    union { unsigned int u; float f; } v; v.u = ((unsigned int)h) << 16;
    return v.f;
}

// ---------------------------------------------------------------------------
// Projection (unchanged, measured good): y = relu(scale*(W x)+bias) -> bf16 hi/lo.
// which 0 (Q) / 1 (K): dst layout [B][N][C]; which 2 (V): dst layout [B][C][N].
// ---------------------------------------------------------------------------
__global__ __launch_bounds__(256) void proj_kernel(
    const float* __restrict__ qf, const float* __restrict__ kf,
    const float* __restrict__ Wq, const float* __restrict__ Wk, const float* __restrict__ Wv,
    const float* __restrict__ sq, const float* __restrict__ bq,
    const float* __restrict__ sk, const float* __restrict__ bk,
    const float* __restrict__ sv, const float* __restrict__ bv,
    unsigned short* __restrict__ Qth, unsigned short* __restrict__ Qtl,
    unsigned short* __restrict__ Kth, unsigned short* __restrict__ Ktl,
    unsigned short* __restrict__ Vh,  unsigned short* __restrict__ Vl)
{
    const int n0 = blockIdx.x * 64;
    const int o0 = blockIdx.y * 64;
    const int z  = blockIdx.z;
    const int which = z % 3;
    const int b     = z / 3;

    const float* W; const float* x; const float* sc; const float* bi;
    unsigned short* dh; unsigned short* dl;
    if (which == 0)      { W = Wq; x = qf; sc = sq; bi = bq; dh = Qth; dl = Qtl; }
    else if (which == 1) { W = Wk; x = kf; sc = sk; bi = bk; dh = Kth; dl = Ktl; }
    else                 { W = Wv; x = kf; sc = sv; bi = bv; dh = Vh;  dl = Vl;  }

    __shared__ float Wt[32][68];
    __shared__ float Xt[32][68];

    const int t  = threadIdx.x;
    const int to = t >> 4;
    const int tn = t & 15;

    const int w_oi  = t >> 2;
    const int w_cc0 = (t & 3) * 8;
    const int x_ci  = t >> 3;
    const int x_no  = (t & 7) * 8;

    float acc[4][4];
#pragma unroll
    for (int i = 0; i < 4; ++i)
#pragma unroll
        for (int j = 0; j < 4; ++j) acc[i][j] = 0.f;

    for (int c0 = 0; c0 < CDIM; c0 += 32) {
        float4 wv[2], xv[2];
#pragma unroll
        for (int v = 0; v < 2; ++v)
            wv[v] = *reinterpret_cast<const float4*>(
                &W[(size_t)(o0 + w_oi) * CDIM + c0 + w_cc0 + 4 * v]);
#pragma unroll
        for (int v = 0; v < 2; ++v)
            xv[v] = *reinterpret_cast<const float4*>(
                &x[((size_t)(b * CDIM + c0 + x_ci)) * NPIX + n0 + x_no + 4 * v]);
        __syncthreads();
#pragma unroll
        for (int v = 0; v < 2; ++v) {
            Wt[w_cc0 + 4 * v + 0][w_oi] = wv[v].x;
            Wt[w_cc0 + 4 * v + 1][w_oi] = wv[v].y;
            Wt[w_cc0 + 4 * v + 2][w_oi] = wv[v].z;
            Wt[w_cc0 + 4 * v + 3][w_oi] = wv[v].w;
            *reinterpret_cast<float4*>(&Xt[x_ci][x_no + 4 * v]) = xv[v];
        }
        __syncthreads();
#pragma unroll
        for (int cc = 0; cc < 32; ++cc) {
            float4 a = *reinterpret_cast<const float4*>(&Wt[cc][4 * to]);
            float4 c = *reinterpret_cast<const float4*>(&Xt[cc][4 * tn]);
            float wa[4] = {a.x, a.y, a.z, a.w};
            float xa[4] = {c.x, c.y, c.z, c.w};
#pragma unroll
            for (int i = 0; i < 4; ++i)
#pragma unroll
                for (int j = 0; j < 4; ++j)
                    acc[i][j] = fmaf(wa[i], xa[j], acc[i][j]);
        }
        __syncthreads();
    }

    unsigned short hi[4][4], lo[4][4];
#pragma unroll
    for (int i = 0; i < 4; ++i) {
        const int o = o0 + 4 * to + i;
        const float s = sc[o], bb = bi[o];
#pragma unroll
        for (int j = 0; j < 4; ++j) {
            float val = fmaxf(fmaf(acc[i][j], s, bb), 0.f);
            unsigned short h = f2bf(val);
            hi[i][j] = h;
            lo[i][j] = f2bf(val - bf2f(h));
        }
    }

    if (which < 2) {
#pragma unroll
        for (int j = 0; j < 4; ++j) {
            const size_t addr = ((size_t)b * NPIX + n0 + 4 * tn + j) * CDIM + o0 + 4 * to;
            ushort4 h4 = make_ushort4(hi[0][j], hi[1][j], hi[2][j], hi[3][j]);
            ushort4 l4 = make_ushort4(lo[0][j], lo[1][j], lo[2][j], lo[3][j]);
            *reinterpret_cast<ushort4*>(&dh[addr]) = h4;
            *reinterpret_cast<ushort4*>(&dl[addr]) = l4;
        }
    } else {
#pragma unroll
        for (int i = 0; i < 4; ++i) {
            const size_t addr = ((size_t)b * CDIM + o0 + 4 * to + i) * NPIX + n0 + 4 * tn;
            ushort4 h4 = make_ushort4(hi[i][0], hi[i][1], hi[i][2], hi[i][3]);
            ushort4 l4 = make_ushort4(lo[i][0], lo[i][1], lo[i][2], lo[i][3]);
            *reinterpret_cast<ushort4*>(&dh[addr]) = h4;
            *reinterpret_cast<ushort4*>(&dl[addr]) = l4;
        }
    }
}

// ---------------------------------------------------------------------------
// MFMA flash attention, split-bf16. Two modes (uniform runtime arg `split`):
//   split=1: 512 blocks = (b, qt, kv-half); writes UNNORMALIZED partial O + m,l.
//   split=0: 256 blocks = (b, qt); full KV sweep, normalizes, writes out.
// LDS = 76.5 KB -> 2 blocks/CU in both modes.
// V tiles: stride 32 elems + 16B-slot XOR swizzle (slot ^= (row>>2)&3):
// staging writes and PV reads both land exactly 8 lanes per 4-bank group.
// ---------------------------------------------------------------------------
__global__ __launch_bounds__(512, 4) void flash_kernel(
    const unsigned short* __restrict__ Qth, const unsigned short* __restrict__ Qtl,
    const unsigned short* __restrict__ Kth, const unsigned short* __restrict__ Ktl,
    const unsigned short* __restrict__ Vh,  const unsigned short* __restrict__ Vl,
    float* __restrict__ Op, float* __restrict__ Mp, float* __restrict__ Lp,
    float* __restrict__ out, int split)
{
    const int bid = blockIdx.x;
    int qt, b, kv, ntiles;
    if (split) {
        // XCD x (= bid&7) owns one (b, kv) pair -> 4 MB K/V set fits its L2.
        const int virt = ((bid & 7) << 6) | (bid >> 3);   // 512 = 8*64, bijective
        qt = virt & 63;
        const int bkv = virt >> 6;
        b = bkv >> 1; kv = bkv & 1; ntiles = KVHALF / KB;
    } else {
        const int virt = ((bid & 7) << 5) | (bid >> 3);   // 256 = 8*32, bijective
        qt = virt & 63; b = virt >> 6; kv = 0; ntiles = NPIX / KB;
    }
    const int qb = qt * QB;
    const int k0 = kv * KVHALF;
    const int pb = b * 64 + qt;      // 0..255

    __shared__ unsigned short Ksh[KB][264], Ksl[KB][264];   // [k][c], 528B rows
    __shared__ unsigned short Vsh[CDIM][32], Vsl[CDIM][32]; // [c][k], swizzled
    __shared__ unsigned short Phs[QB][40],  Pls[QB][40];    // [q][k]
    __shared__ float Msh[2][QB], Ssh2[2][QB], Rsh[QB], Linv[QB];

    const int t    = threadIdx.x;
    const int w    = t >> 6;
    const int lane = t & 63;
    const int g    = lane >> 4;
    const int li   = lane & 15;

    const int smq = w & 3, snk = w >> 2;   // S roles
    const int pqf = w & 3, pch = w >> 2;   // PV roles

    // staging coords
    const int krow = t >> 4, kcol = (t & 15) * 16;  // K tile: 32 x 256
    const int vrow = t >> 1, vcol = (t & 1) * 16;   // V tile: 256 x 32
    const int vsw  = (vrow >> 2) & 3;
    const int vp0  = ((2 * (t & 1) + 0) ^ vsw) * 8; // physical elem offsets
    const int vp1  = ((2 * (t & 1) + 1) ^ vsw) * 8;
    const int pg   = (g ^ ((li >> 2) & 3)) * 8;     // PV read swizzle

    // ---- Q fragments in registers for the whole k-loop ----
    short8 qh[8], ql[8];
    {
        const size_t qbase = ((size_t)b * NPIX + qb + smq * 16 + li) * CDIM + g * 8;
#pragma unroll
        for (int cs = 0; cs < 8; ++cs) {
            qh[cs] = *reinterpret_cast<const short8*>(&Qth[qbase + cs * 32]);
            ql[cs] = *reinterpret_cast<const short8*>(&Qtl[qbase + cs * 32]);
        }
    }

    f32x4 O[8];
#pragma unroll
    for (int fi = 0; fi < 8; ++fi) O[fi] = (f32x4){0.f, 0.f, 0.f, 0.f};

    float m_run[4], l_run[4];
#pragma unroll
    for (int r = 0; r < 4; ++r) { m_run[r] = -INFINITY; l_run[r] = 0.f; }

    const float scl = 0.0625f;  // C^-0.5

    uint4 rKh0, rKh1, rKl0, rKl1, rVh0, rVh1, rVl0, rVl1;
    const size_t kgbase = ((size_t)b * NPIX + k0 + krow) * CDIM + kcol;
    const size_t vgbase = ((size_t)(b * CDIM + vrow)) * NPIX + k0 + vcol;

    {
        rKh0 = *reinterpret_cast<const uint4*>(&Kth[kgbase]);
        rKh1 = *reinterpret_cast<const uint4*>(&Kth[kgbase + 8]);
        rKl0 = *reinterpret_cast<const uint4*>(&Ktl[kgbase]);
        rKl1 = *reinterpret_cast<const uint4*>(&Ktl[kgbase + 8]);
        rVh0 = *reinterpret_cast<const uint4*>(&Vh[vgbase]);
        rVh1 = *reinterpret_cast<const uint4*>(&Vh[vgbase + 8]);
        rVl0 = *reinterpret_cast<const uint4*>(&Vl[vgbase]);
        rVl1 = *reinterpret_cast<const uint4*>(&Vl[vgbase + 8]);
    }

    for (int it = 0; it < ntiles; ++it) {
        // ---- write staged tile to LDS ----
        *reinterpret_cast<uint4*>(&Ksh[krow][kcol])     = rKh0;
        *reinterpret_cast<uint4*>(&Ksh[krow][kcol + 8]) = rKh1;
        *reinterpret_cast<uint4*>(&Ksl[krow][kcol])     = rKl0;
        *reinterpret_cast<uint4*>(&Ksl[krow][kcol + 8]) = rKl1;
        *reinterpret_cast<uint4*>(&Vsh[vrow][vp0])      = rVh0;
        *reinterpret_cast<uint4*>(&Vsh[vrow][vp1])      = rVh1;
        *reinterpret_cast<uint4*>(&Vsl[vrow][vp0])      = rVl0;
        *reinterpret_cast<uint4*>(&Vsl[vrow][vp1])      = rVl1;
        __syncthreads();  // B0

        // ---- S = Q^T K  (split: qh*kh + ql*kh + qh*kl) ----
        f32x4 sacc = (f32x4){0.f, 0.f, 0.f, 0.f};
#pragma unroll
        for (int cs = 0; cs < 8; ++cs) {
            short8 kbh = *reinterpret_cast<const short8*>(&Ksh[snk * 16 + li][cs * 32 + g * 8]);
            short8 kbl = *reinterpret_cast<const short8*>(&Ksl[snk * 16 + li][cs * 32 + g * 8]);
            sacc = MFMA(qh[cs], kbh, sacc);
            sacc = MFMA(ql[cs], kbh, sacc);
            sacc = MFMA(qh[cs], kbl, sacc);
        }

        // ---- prefetch next tile's K/V (latency hides under softmax + PV) ----
        {
            const int ktn = (it + 1 < ntiles) ? (it + 1) * KB : 0;
            const size_t ka = kgbase + (size_t)ktn * CDIM;
            rKh0 = *reinterpret_cast<const uint4*>(&Kth[ka]);
            rKh1 = *reinterpret_cast<const uint4*>(&Kth[ka + 8]);
            rKl0 = *reinterpret_cast<const uint4*>(&Ktl[ka]);
            rKl1 = *reinterpret_cast<const uint4*>(&Ktl[ka + 8]);
            const size_t va = vgbase + ktn;
            rVh0 = *reinterpret_cast<const uint4*>(&Vh[va]);
            rVh1 = *reinterpret_cast<const uint4*>(&Vh[va + 8]);
            rVl0 = *reinterpret_cast<const uint4*>(&Vl[va]);
            rVl1 = *reinterpret_cast<const uint4*>(&Vl[va + 8]);
        }

        // ---- online softmax ----
        float sv[4], mx[4];
#pragma unroll
        for (int r = 0; r < 4; ++r) { sv[r] = sacc[r] * scl; mx[r] = sv[r]; }
#pragma unroll
        for (int d = 1; d < 16; d <<= 1)
#pragma unroll
            for (int r = 0; r < 4; ++r) mx[r] = fmaxf(mx[r], __shfl_xor(mx[r], d, 64));

        if (li == 0) {
#pragma unroll
            for (int r = 0; r < 4; ++r) Msh[snk][smq * 16 + g * 4 + r] = mx[r];
        }
        __syncthreads();  // B1

        float p[4], resc[4], psum[4];
#pragma unroll
        for (int r = 0; r < 4; ++r) {
            const int q = smq * 16 + g * 4 + r;
            const float mt = fmaxf(Msh[0][q], Msh[1][q]);
            const float mn = fmaxf(m_run[r], mt);
            resc[r] = __expf(m_run[r] - mn);
            m_run[r] = mn;
            p[r] = __expf(sv[r] - mn);
            psum[r] = p[r];
        }
#pragma unroll
        for (int d = 1; d < 16; d <<= 1)
#pragma unroll
            for (int r = 0; r < 4; ++r) psum[r] += __shfl_xor(psum[r], d, 64);

#pragma unroll
        for (int r = 0; r < 4; ++r) {
            const int q = smq * 16 + g * 4 + r;
            unsigned short ph = f2bf(p[r]);
            Phs[q][snk * 16 + li] = ph;
            Pls[q][snk * 16 + li] = f2bf(p[r] - bf2f(ph));
        }
        if (li == 0) {
#pragma unroll
            for (int r = 0; r < 4; ++r) {
                const int q = smq * 16 + g * 4 + r;
                Ssh2[snk][q] = psum[r];
                if (snk == 0) Rsh[q] = resc[r];
            }
        }
        __syncthreads();  // B2

        // ---- l update ----
#pragma unroll
        for (int r = 0; r < 4; ++r) {
            const int q = smq * 16 + g * 4 + r;
            l_run[r] = l_run[r] * resc[r] + Ssh2[0][q] + Ssh2[1][q];
        }

        // ---- PV: O[c][q] += V[c][k] P[q][k] ----
        const float rf = Rsh[pqf * 16 + li];
        short8 pa = *reinterpret_cast<const short8*>(&Phs[pqf * 16 + li][g * 8]);
        short8 pb2 = *reinterpret_cast<const short8*>(&Pls[pqf * 16 + li][g * 8]);
#pragma unroll
        for (int fi = 0; fi < 8; ++fi) {
            O[fi] = O[fi] * rf;
            const int crow = (pch * 8 + fi) * 16 + li;
            short8 va = *reinterpret_cast<const short8*>(&Vsh[crow][pg]);
            short8 vb = *reinterpret_cast<const short8*>(&Vsl[crow][pg]);
            O[fi] = MFMA(va, pa, O[fi]);
            O[fi] = MFMA(vb, pa, O[fi]);
            O[fi] = MFMA(va, pb2, O[fi]);
        }
        __syncthreads();  // B3
    }

    if (split) {
        // ---- epilogue A: unnormalized partial O + per-row (m, l) ----
        const size_t obase = ((size_t)(kv * 256 + pb)) * 256;
#pragma unroll
        for (int fi = 0; fi < 8; ++fi) {
#pragma unroll
            for (int r = 0; r < 4; ++r) {
                const int c = (pch * 8 + fi) * 16 + g * 4 + r;
                Op[(obase + c) * 64 + pqf * 16 + li] = O[fi][r];
            }
        }
        if (snk == 0 && li == 0) {
            const size_t mlbase = ((size_t)(kv * 256 + pb)) * 64;
#pragma unroll
            for (int r = 0; r < 4; ++r) {
                const int q = smq * 16 + g * 4 + r;
                Mp[mlbase + q] = m_run[r];
                Lp[mlbase + q] = l_run[r];
            }
        }
    } else {
        // ---- epilogue B: normalize in-kernel, write out directly ----
        if (snk == 0 && li == 0) {
#pragma unroll
            for (int r = 0; r < 4; ++r)
                Linv[smq * 16 + g * 4 + r] = 1.0f / l_run[r];
        }
        __syncthreads();
        const float linv = Linv[pqf * 16 + li];
#pragma unroll
        for (int fi = 0; fi < 8; ++fi) {
#pragma unroll
            for (int r = 0; r < 4; ++r) {
                const int c = (pch * 8 + fi) * 16 + g * 4 + r;
                out[((size_t)(b * CDIM + c)) * NPIX + qb + pqf * 16 + li] = O[fi][r] * linv;
            }
        }
    }
}

// ---------------------------------------------------------------------------
// Merge the two kv-half partials: out = (O0*a0 + O1*a1) / (l0*a0 + l1*a1),
// a_h = exp(m_h - max(m0,m1)). Memory-bound (~50 MB).
// ---------------------------------------------------------------------------
__global__ __launch_bounds__(256) void merge_kernel(
    const float* __restrict__ Op, const float* __restrict__ Mp, const float* __restrict__ Lp,
    float* __restrict__ out)
{
    const int idx = blockIdx.x * 256 + threadIdx.x;  // float4 index
    const int qq4 = idx & 15;
    const int c   = (idx >> 4) & 255;
    const int pb  = idx >> 12;           // b*64+qt
    const int b   = pb >> 6;
    const int qt  = pb & 63;

    const size_t o0 = (((size_t)pb) * 256 + c) * 64 + qq4 * 4;
    const size_t o1 = (((size_t)(256 + pb)) * 256 + c) * 64 + qq4 * 4;
    float4 v0 = *reinterpret_cast<const float4*>(&Op[o0]);
    float4 v1 = *reinterpret_cast<const float4*>(&Op[o1]);

    const size_t ml0 = ((size_t)pb) * 64 + qq4 * 4;
    const size_t ml1 = ((size_t)(256 + pb)) * 64 + qq4 * 4;
    float4 m0 = *reinterpret_cast<const float4*>(&Mp[ml0]);
    float4 m1 = *reinterpret_cast<const float4*>(&Mp[ml1]);
    float4 l0 = *reinterpret_cast<const float4*>(&Lp[ml0]);
    float4 l1 = *reinterpret_cast<const float4*>(&Lp[ml1]);

    float4 r;
    {
        float M = fmaxf(m0.x, m1.x), a0 = __expf(m0.x - M), a1 = __expf(m1.x - M);
        r.x = (v0.x * a0 + v1.x * a1) / (l0.x * a0 + l1.x * a1);
    }
    {
        float M = fmaxf(m0.y, m1.y), a0 = __expf(m0.y - M), a1 = __expf(m1.y - M);
        r.y = (v0.y * a0 + v1.y * a1) / (l0.y * a0 + l1.y * a1);
    }
    {
        float M = fmaxf(m0.z, m1.z), a0 = __expf(m0.z - M), a1 = __expf(m1.z - M);
        r.z = (v0.z * a0 + v1.z * a1) / (l0.z * a0 + l1.z * a1);
    }
    {
        float M = fmaxf(m0.w, m1.w), a0 = __expf(m0.w - M), a1 = __expf(m1.w - M);
        r.w = (v0.w * a0 + v1.w * a1) / (l0.w * a0 + l1.w * a1);
    }

    *reinterpret_cast<float4*>(&out[((size_t)(b * CDIM + c)) * NPIX + qt * 64 + qq4 * 4]) = r;
}

// ---------------------------------------------------------------------------
extern "C" void kernel_launch(void* const* d_in, const int* in_sizes, int n_in,
                              void* d_out, int out_size, void* d_ws, size_t ws_size,
                              hipStream_t stream)
{
    const float* qf = (const float*)d_in[0];
    const float* kf = (const float*)d_in[1];
    const float* Wq = (const float*)d_in[2];
    const float* Wk = (const float*)d_in[3];
    const float* Wv = (const float*)d_in[4];
    const float* sq = (const float*)d_in[5];
    const float* bq = (const float*)d_in[6];
    const float* sk = (const float*)d_in[7];
    const float* bk = (const float*)d_in[8];
    const float* sv = (const float*)d_in[9];
    const float* bv = (const float*)d_in[10];
    float* out = (float*)d_out;

    // ws layout: 6 bf16 planes (50.3 MB) [+ split: Op 33.6 MB + Mp/Lp 0.26 MB]
    const size_t plane = (size_t)BATCH * CDIM * NPIX;  // 4,194,304 elems
    unsigned short* ws = (unsigned short*)d_ws;
    unsigned short* Qth = ws;
    unsigned short* Qtl = ws + plane;
    unsigned short* Kth = ws + 2 * plane;
    unsigned short* Ktl = ws + 3 * plane;
    unsigned short* Vh  = ws + 4 * plane;
    unsigned short* Vl  = ws + 5 * plane;
    float* Op = (float*)(ws + 6 * plane);              // 512*256*64 floats
    float* Mp = Op + (size_t)512 * 256 * 64;
    float* Lp = Mp + (size_t)512 * 64;

    const size_t need = 6 * plane * sizeof(unsigned short)
                      + ((size_t)512 * 256 * 64 + 2 * (size_t)512 * 64) * sizeof(float);
    const int split = (ws_size >= need) ? 1 : 0;  // ws_size fixed -> same path every call

    dim3 gp(NPIX / 64, CDIM / 64, 3 * BATCH);
    proj_kernel<<<gp, 256, 0, stream>>>(qf, kf, Wq, Wk, Wv, sq, bq, sk, bk, sv, bv,
                                        Qth, Qtl, Kth, Ktl, Vh, Vl);

    if (split) {
        flash_kernel<<<dim3(512), 512, 0, stream>>>(Qth, Qtl, Kth, Ktl, Vh, Vl,
                                                    Op, Mp, Lp, out, 1);
        merge_kernel<<<dim3(4096), 256, 0, stream>>>(Op, Mp, Lp, out);
    } else {
        flash_kernel<<<dim3(256), 512, 0, stream>>>(Qth, Qtl, Kth, Ktl, Vh, Vl,
                                                    Op, Mp, Lp, out, 0);
    }
}

// Round 9
// 612.904 us; speedup vs baseline: 1.5098x; 1.5098x over previous
//
#include <hip/hip_runtime.h>
#include <math.h>

#define CDIM 256
#define NPIX 4096
#define BATCH 4
#define QB 64
#define KB 32
#define KVHALF 2048

typedef __attribute__((ext_vector_type(8))) short short8;
typedef __attribute__((ext_vector_type(4))) float f32x4;
#define MFMA(a, b, c) __builtin_amdgcn_mfma_f32_16x16x32_bf16((a), (b), (c), 0, 0, 0)

__device__ __forceinline__ unsigned short f2bf(float f) {
    union { float f; unsigned int u; } v; v.f = f;
    unsigned int u = v.u;
    return (unsigned short)((u + 0x7FFFu + ((u >> 16) & 1u)) >> 16);
}
__device__ __forceinline__ float bf2f(unsigned short h) {
    union { unsigned int u; float f; } v; v.u = ((unsigned int)h) << 16;
    return v.f;
}

// ---------------------------------------------------------------------------
// Projection (unchanged, measured good): y = relu(scale*(W x)+bias) -> bf16 hi/lo.
// which 0 (Q) / 1 (K): dst layout [B][N][C]; which 2 (V): dst layout [B][C][N].
// ---------------------------------------------------------------------------
__global__ __launch_bounds__(256) void proj_kernel(
    const float* __restrict__ qf, const float* __restrict__ kf,
    const float* __restrict__ Wq, const float* __restrict__ Wk, const float* __restrict__ Wv,
    const float* __restrict__ sq, const float* __restrict__ bq,
    const float* __restrict__ sk, const float* __restrict__ bk,
    const float* __restrict__ sv, const float* __restrict__ bv,
    unsigned short* __restrict__ Qth, unsigned short* __restrict__ Qtl,
    unsigned short* __restrict__ Kth, unsigned short* __restrict__ Ktl,
    unsigned short* __restrict__ Vh,  unsigned short* __restrict__ Vl)
{
    const int n0 = blockIdx.x * 64;
    const int o0 = blockIdx.y * 64;
    const int z  = blockIdx.z;
    const int which = z % 3;
    const int b     = z / 3;

    const float* W; const float* x; const float* sc; const float* bi;
    unsigned short* dh; unsigned short* dl;
    if (which == 0)      { W = Wq; x = qf; sc = sq; bi = bq; dh = Qth; dl = Qtl; }
    else if (which == 1) { W = Wk; x = kf; sc = sk; bi = bk; dh = Kth; dl = Ktl; }
    else                 { W = Wv; x = kf; sc = sv; bi = bv; dh = Vh;  dl = Vl;  }

    __shared__ float Wt[32][68];
    __shared__ float Xt[32][68];

    const int t  = threadIdx.x;
    const int to = t >> 4;
    const int tn = t & 15;

    const int w_oi  = t >> 2;
    const int w_cc0 = (t & 3) * 8;
    const int x_ci  = t >> 3;
    const int x_no  = (t & 7) * 8;

    float acc[4][4];
#pragma unroll
    for (int i = 0; i < 4; ++i)
#pragma unroll
        for (int j = 0; j < 4; ++j) acc[i][j] = 0.f;

    for (int c0 = 0; c0 < CDIM; c0 += 32) {
        float4 wv[2], xv[2];
#pragma unroll
        for (int v = 0; v < 2; ++v)
            wv[v] = *reinterpret_cast<const float4*>(
                &W[(size_t)(o0 + w_oi) * CDIM + c0 + w_cc0 + 4 * v]);
#pragma unroll
        for (int v = 0; v < 2; ++v)
            xv[v] = *reinterpret_cast<const float4*>(
                &x[((size_t)(b * CDIM + c0 + x_ci)) * NPIX + n0 + x_no + 4 * v]);
        __syncthreads();
#pragma unroll
        for (int v = 0; v < 2; ++v) {
            Wt[w_cc0 + 4 * v + 0][w_oi] = wv[v].x;
            Wt[w_cc0 + 4 * v + 1][w_oi] = wv[v].y;
            Wt[w_cc0 + 4 * v + 2][w_oi] = wv[v].z;
            Wt[w_cc0 + 4 * v + 3][w_oi] = wv[v].w;
            *reinterpret_cast<float4*>(&Xt[x_ci][x_no + 4 * v]) = xv[v];
        }
        __syncthreads();
#pragma unroll
        for (int cc = 0; cc < 32; ++cc) {
            float4 a = *reinterpret_cast<const float4*>(&Wt[cc][4 * to]);
            float4 c = *reinterpret_cast<const float4*>(&Xt[cc][4 * tn]);
            float wa[4] = {a.x, a.y, a.z, a.w};
            float xa[4] = {c.x, c.y, c.z, c.w};
#pragma unroll
            for (int i = 0; i < 4; ++i)
#pragma unroll
                for (int j = 0; j < 4; ++j)
                    acc[i][j] = fmaf(wa[i], xa[j], acc[i][j]);
        }
        __syncthreads();
    }

    unsigned short hi[4][4], lo[4][4];
#pragma unroll
    for (int i = 0; i < 4; ++i) {
        const int o = o0 + 4 * to + i;
        const float s = sc[o], bb = bi[o];
#pragma unroll
        for (int j = 0; j < 4; ++j) {
            float val = fmaxf(fmaf(acc[i][j], s, bb), 0.f);
            unsigned short h = f2bf(val);
            hi[i][j] = h;
            lo[i][j] = f2bf(val - bf2f(h));
        }
    }

    if (which < 2) {
#pragma unroll
        for (int j = 0; j < 4; ++j) {
            const size_t addr = ((size_t)b * NPIX + n0 + 4 * tn + j) * CDIM + o0 + 4 * to;
            ushort4 h4 = make_ushort4(hi[0][j], hi[1][j], hi[2][j], hi[3][j]);
            ushort4 l4 = make_ushort4(lo[0][j], lo[1][j], lo[2][j], lo[3][j]);
            *reinterpret_cast<ushort4*>(&dh[addr]) = h4;
            *reinterpret_cast<ushort4*>(&dl[addr]) = l4;
        }
    } else {
#pragma unroll
        for (int i = 0; i < 4; ++i) {
            const size_t addr = ((size_t)b * CDIM + o0 + 4 * to + i) * NPIX + n0 + 4 * tn;
            ushort4 h4 = make_ushort4(hi[i][0], hi[i][1], hi[i][2], hi[i][3]);
            ushort4 l4 = make_ushort4(lo[i][0], lo[i][1], lo[i][2], lo[i][3]);
            *reinterpret_cast<ushort4*>(&dh[addr]) = h4;
            *reinterpret_cast<ushort4*>(&dl[addr]) = l4;
        }
    }
}

// ---------------------------------------------------------------------------
// MFMA flash attention, split-bf16. Two modes (uniform runtime arg `split`):
//   split=1: 512 blocks = (b, qt, kv-half); writes UNNORMALIZED partial O + m,l.
//   split=0: 256 blocks = (b, qt); full KV sweep, normalizes, writes out.
// LDS = 76.5 KB; VGPR ~104 (launch_bounds(512,2): R5's (512,4) clamped arch
// VGPRs to 64 -> Q-frag spill -> 1.9 GB scratch traffic. Do NOT re-tighten.)
// -> 2 blocks/CU from LDS+VGPR naturally.
// V tiles: stride 32 elems + 16B-slot XOR swizzle (slot ^= (row>>2)&3):
// staging writes and PV reads both land exactly 8 lanes per 4-bank group.
// ---------------------------------------------------------------------------
__global__ __launch_bounds__(512, 2) void flash_kernel(
    const unsigned short* __restrict__ Qth, const unsigned short* __restrict__ Qtl,
    const unsigned short* __restrict__ Kth, const unsigned short* __restrict__ Ktl,
    const unsigned short* __restrict__ Vh,  const unsigned short* __restrict__ Vl,
    float* __restrict__ Op, float* __restrict__ Mp, float* __restrict__ Lp,
    float* __restrict__ out, int split)
{
    const int bid = blockIdx.x;
    int qt, b, kv, ntiles;
    if (split) {
        // XCD x (= bid&7) owns one (b, kv) pair -> 4 MB K/V set fits its L2.
        const int virt = ((bid & 7) << 6) | (bid >> 3);   // 512 = 8*64, bijective
        qt = virt & 63;
        const int bkv = virt >> 6;
        b = bkv >> 1; kv = bkv & 1; ntiles = KVHALF / KB;
    } else {
        const int virt = ((bid & 7) << 5) | (bid >> 3);   // 256 = 8*32, bijective
        qt = virt & 63; b = virt >> 6; kv = 0; ntiles = NPIX / KB;
    }
    const int qb = qt * QB;
    const int k0 = kv * KVHALF;
    const int pb = b * 64 + qt;      // 0..255

    __shared__ unsigned short Ksh[KB][264], Ksl[KB][264];   // [k][c], 528B rows
    __shared__ unsigned short Vsh[CDIM][32], Vsl[CDIM][32]; // [c][k], swizzled
    __shared__ unsigned short Phs[QB][40],  Pls[QB][40];    // [q][k]
    __shared__ float Msh[2][QB], Ssh2[2][QB], Rsh[QB], Linv[QB];

    const int t    = threadIdx.x;
    const int w    = t >> 6;
    const int lane = t & 63;
    const int g    = lane >> 4;
    const int li   = lane & 15;

    const int smq = w & 3, snk = w >> 2;   // S roles
    const int pqf = w & 3, pch = w >> 2;   // PV roles

    // staging coords
    const int krow = t >> 4, kcol = (t & 15) * 16;  // K tile: 32 x 256
    const int vrow = t >> 1, vcol = (t & 1) * 16;   // V tile: 256 x 32
    const int vsw  = (vrow >> 2) & 3;
    const int vp0  = ((2 * (t & 1) + 0) ^ vsw) * 8; // physical elem offsets
    const int vp1  = ((2 * (t & 1) + 1) ^ vsw) * 8;
    const int pg   = (g ^ ((li >> 2) & 3)) * 8;     // PV read swizzle

    // ---- Q fragments in registers for the whole k-loop ----
    short8 qh[8], ql[8];
    {
        const size_t qbase = ((size_t)b * NPIX + qb + smq * 16 + li) * CDIM + g * 8;
#pragma unroll
        for (int cs = 0; cs < 8; ++cs) {
            qh[cs] = *reinterpret_cast<const short8*>(&Qth[qbase + cs * 32]);
            ql[cs] = *reinterpret_cast<const short8*>(&Qtl[qbase + cs * 32]);
        }
    }

    f32x4 O[8];
#pragma unroll
    for (int fi = 0; fi < 8; ++fi) O[fi] = (f32x4){0.f, 0.f, 0.f, 0.f};

    float m_run[4], l_run[4];
#pragma unroll
    for (int r = 0; r < 4; ++r) { m_run[r] = -INFINITY; l_run[r] = 0.f; }

    const float scl = 0.0625f;  // C^-0.5

    uint4 rKh0, rKh1, rKl0, rKl1, rVh0, rVh1, rVl0, rVl1;
    const size_t kgbase = ((size_t)b * NPIX + k0 + krow) * CDIM + kcol;
    const size_t vgbase = ((size_t)(b * CDIM + vrow)) * NPIX + k0 + vcol;

    {
        rKh0 = *reinterpret_cast<const uint4*>(&Kth[kgbase]);
        rKh1 = *reinterpret_cast<const uint4*>(&Kth[kgbase + 8]);
        rKl0 = *reinterpret_cast<const uint4*>(&Ktl[kgbase]);
        rKl1 = *reinterpret_cast<const uint4*>(&Ktl[kgbase + 8]);
        rVh0 = *reinterpret_cast<const uint4*>(&Vh[vgbase]);
        rVh1 = *reinterpret_cast<const uint4*>(&Vh[vgbase + 8]);
        rVl0 = *reinterpret_cast<const uint4*>(&Vl[vgbase]);
        rVl1 = *reinterpret_cast<const uint4*>(&Vl[vgbase + 8]);
    }

    for (int it = 0; it < ntiles; ++it) {
        // ---- write staged tile to LDS ----
        *reinterpret_cast<uint4*>(&Ksh[krow][kcol])     = rKh0;
        *reinterpret_cast<uint4*>(&Ksh[krow][kcol + 8]) = rKh1;
        *reinterpret_cast<uint4*>(&Ksl[krow][kcol])     = rKl0;
        *reinterpret_cast<uint4*>(&Ksl[krow][kcol + 8]) = rKl1;
        *reinterpret_cast<uint4*>(&Vsh[vrow][vp0])      = rVh0;
        *reinterpret_cast<uint4*>(&Vsh[vrow][vp1])      = rVh1;
        *reinterpret_cast<uint4*>(&Vsl[vrow][vp0])      = rVl0;
        *reinterpret_cast<uint4*>(&Vsl[vrow][vp1])      = rVl1;
        __syncthreads();  // B0

        // ---- S = Q^T K  (split: qh*kh + ql*kh + qh*kl) ----
        f32x4 sacc = (f32x4){0.f, 0.f, 0.f, 0.f};
#pragma unroll
        for (int cs = 0; cs < 8; ++cs) {
            short8 kbh = *reinterpret_cast<const short8*>(&Ksh[snk * 16 + li][cs * 32 + g * 8]);
            short8 kbl = *reinterpret_cast<const short8*>(&Ksl[snk * 16 + li][cs * 32 + g * 8]);
            sacc = MFMA(qh[cs], kbh, sacc);
            sacc = MFMA(ql[cs], kbh, sacc);
            sacc = MFMA(qh[cs], kbl, sacc);
        }

        // ---- prefetch next tile's K/V (latency hides under softmax + PV) ----
        {
            const int ktn = (it + 1 < ntiles) ? (it + 1) * KB : 0;
            const size_t ka = kgbase + (size_t)ktn * CDIM;
            rKh0 = *reinterpret_cast<const uint4*>(&Kth[ka]);
            rKh1 = *reinterpret_cast<const uint4*>(&Kth[ka + 8]);
            rKl0 = *reinterpret_cast<const uint4*>(&Ktl[ka]);
            rKl1 = *reinterpret_cast<const uint4*>(&Ktl[ka + 8]);
            const size_t va = vgbase + ktn;
            rVh0 = *reinterpret_cast<const uint4*>(&Vh[va]);
            rVh1 = *reinterpret_cast<const uint4*>(&Vh[va + 8]);
            rVl0 = *reinterpret_cast<const uint4*>(&Vl[va]);
            rVl1 = *reinterpret_cast<const uint4*>(&Vl[va + 8]);
        }

        // ---- online softmax ----
        float sv[4], mx[4];
#pragma unroll
        for (int r = 0; r < 4; ++r) { sv[r] = sacc[r] * scl; mx[r] = sv[r]; }
#pragma unroll
        for (int d = 1; d < 16; d <<= 1)
#pragma unroll
            for (int r = 0; r < 4; ++r) mx[r] = fmaxf(mx[r], __shfl_xor(mx[r], d, 64));

        if (li == 0) {
#pragma unroll
            for (int r = 0; r < 4; ++r) Msh[snk][smq * 16 + g * 4 + r] = mx[r];
        }
        __syncthreads();  // B1

        float p[4], resc[4], psum[4];
#pragma unroll
        for (int r = 0; r < 4; ++r) {
            const int q = smq * 16 + g * 4 + r;
            const float mt = fmaxf(Msh[0][q], Msh[1][q]);
            const float mn = fmaxf(m_run[r], mt);
            resc[r] = __expf(m_run[r] - mn);
            m_run[r] = mn;
            p[r] = __expf(sv[r] - mn);
            psum[r] = p[r];
        }
#pragma unroll
        for (int d = 1; d < 16; d <<= 1)
#pragma unroll
            for (int r = 0; r < 4; ++r) psum[r] += __shfl_xor(psum[r], d, 64);

#pragma unroll
        for (int r = 0; r < 4; ++r) {
            const int q = smq * 16 + g * 4 + r;
            unsigned short ph = f2bf(p[r]);
            Phs[q][snk * 16 + li] = ph;
            Pls[q][snk * 16 + li] = f2bf(p[r] - bf2f(ph));
        }
        if (li == 0) {
#pragma unroll
            for (int r = 0; r < 4; ++r) {
                const int q = smq * 16 + g * 4 + r;
                Ssh2[snk][q] = psum[r];
                if (snk == 0) Rsh[q] = resc[r];
            }
        }
        __syncthreads();  // B2

        // ---- l update ----
#pragma unroll
        for (int r = 0; r < 4; ++r) {
            const int q = smq * 16 + g * 4 + r;
            l_run[r] = l_run[r] * resc[r] + Ssh2[0][q] + Ssh2[1][q];
        }

        // ---- PV: O[c][q] += V[c][k] P[q][k] ----
        const float rf = Rsh[pqf * 16 + li];
        short8 pa = *reinterpret_cast<const short8*>(&Phs[pqf * 16 + li][g * 8]);
        short8 pb2 = *reinterpret_cast<const short8*>(&Pls[pqf * 16 + li][g * 8]);
#pragma unroll
        for (int fi = 0; fi < 8; ++fi) {
            O[fi] = O[fi] * rf;
            const int crow = (pch * 8 + fi) * 16 + li;
            short8 va = *reinterpret_cast<const short8*>(&Vsh[crow][pg]);
            short8 vb = *reinterpret_cast<const short8*>(&Vsl[crow][pg]);
            O[fi] = MFMA(va, pa, O[fi]);
            O[fi] = MFMA(vb, pa, O[fi]);
            O[fi] = MFMA(va, pb2, O[fi]);
        }
        __syncthreads();  // B3
    }

    if (split) {
        // ---- epilogue A: unnormalized partial O + per-row (m, l) ----
        const size_t obase = ((size_t)(kv * 256 + pb)) * 256;
#pragma unroll
        for (int fi = 0; fi < 8; ++fi) {
#pragma unroll
            for (int r = 0; r < 4; ++r) {
                const int c = (pch * 8 + fi) * 16 + g * 4 + r;
                Op[(obase + c) * 64 + pqf * 16 + li] = O[fi][r];
            }
        }
        if (snk == 0 && li == 0) {
            const size_t mlbase = ((size_t)(kv * 256 + pb)) * 64;
#pragma unroll
            for (int r = 0; r < 4; ++r) {
                const int q = smq * 16 + g * 4 + r;
                Mp[mlbase + q] = m_run[r];
                Lp[mlbase + q] = l_run[r];
            }
        }
    } else {
        // ---- epilogue B: normalize in-kernel, write out directly ----
        if (snk == 0 && li == 0) {
#pragma unroll
            for (int r = 0; r < 4; ++r)
                Linv[smq * 16 + g * 4 + r] = 1.0f / l_run[r];
        }
        __syncthreads();
        const float linv = Linv[pqf * 16 + li];
#pragma unroll
        for (int fi = 0; fi < 8; ++fi) {
#pragma unroll
            for (int r = 0; r < 4; ++r) {
                const int c = (pch * 8 + fi) * 16 + g * 4 + r;
                out[((size_t)(b * CDIM + c)) * NPIX + qb + pqf * 16 + li] = O[fi][r] * linv;
            }
        }
    }
}

// ---------------------------------------------------------------------------
// Merge the two kv-half partials: out = (O0*a0 + O1*a1) / (l0*a0 + l1*a1),
// a_h = exp(m_h - max(m0,m1)). Memory-bound (~50 MB).
// ---------------------------------------------------------------------------
__global__ __launch_bounds__(256) void merge_kernel(
    const float* __restrict__ Op, const float* __restrict__ Mp, const float* __restrict__ Lp,
    float* __restrict__ out)
{
    const int idx = blockIdx.x * 256 + threadIdx.x;  // float4 index
    const int qq4 = idx & 15;
    const int c   = (idx >> 4) & 255;
    const int pb  = idx >> 12;           // b*64+qt
    const int b   = pb >> 6;
    const int qt  = pb & 63;

    const size_t o0 = (((size_t)pb) * 256 + c) * 64 + qq4 * 4;
    const size_t o1 = (((size_t)(256 + pb)) * 256 + c) * 64 + qq4 * 4;
    float4 v0 = *reinterpret_cast<const float4*>(&Op[o0]);
    float4 v1 = *reinterpret_cast<const float4*>(&Op[o1]);

    const size_t ml0 = ((size_t)pb) * 64 + qq4 * 4;
    const size_t ml1 = ((size_t)(256 + pb)) * 64 + qq4 * 4;
    float4 m0 = *reinterpret_cast<const float4*>(&Mp[ml0]);
    float4 m1 = *reinterpret_cast<const float4*>(&Mp[ml1]);
    float4 l0 = *reinterpret_cast<const float4*>(&Lp[ml0]);
    float4 l1 = *reinterpret_cast<const float4*>(&Lp[ml1]);

    float4 r;
    {
        float M = fmaxf(m0.x, m1.x), a0 = __expf(m0.x - M), a1 = __expf(m1.x - M);
        r.x = (v0.x * a0 + v1.x * a1) / (l0.x * a0 + l1.x * a1);
    }
    {
        float M = fmaxf(m0.y, m1.y), a0 = __expf(m0.y - M), a1 = __expf(m1.y - M);
        r.y = (v0.y * a0 + v1.y * a1) / (l0.y * a0 + l1.y * a1);
    }
    {
        float M = fmaxf(m0.z, m1.z), a0 = __expf(m0.z - M), a1 = __expf(m1.z - M);
        r.z = (v0.z * a0 + v1.z * a1) / (l0.z * a0 + l1.z * a1);
    }
    {
        float M = fmaxf(m0.w, m1.w), a0 = __expf(m0.w - M), a1 = __expf(m1.w - M);
        r.w = (v0.w * a0 + v1.w * a1) / (l0.w * a0 + l1.w * a1);
    }

    *reinterpret_cast<float4*>(&out[((size_t)(b * CDIM + c)) * NPIX + qt * 64 + qq4 * 4]) = r;
}

// ---------------------------------------------------------------------------
extern "C" void kernel_launch(void* const* d_in, const int* in_sizes, int n_in,
                              void* d_out, int out_size, void* d_ws, size_t ws_size,
                              hipStream_t stream)
{
    const float* qf = (const float*)d_in[0];
    const float* kf = (const float*)d_in[1];
    const float* Wq = (const float*)d_in[2];
    const float* Wk = (const float*)d_in[3];
    const float* Wv = (const float*)d_in[4];
    const float* sq = (const float*)d_in[5];
    const float* bq = (const float*)d_in[6];
    const float* sk = (const float*)d_in[7];
    const float* bk = (const float*)d_in[8];
    const float* sv = (const float*)d_in[9];
    const float* bv = (const float*)d_in[10];
    float* out = (float*)d_out;

    // ws layout: 6 bf16 planes (50.3 MB) [+ split: Op 33.6 MB + Mp/Lp 0.26 MB]
    const size_t plane = (size_t)BATCH * CDIM * NPIX;  // 4,194,304 elems
    unsigned short* ws = (unsigned short*)d_ws;
    unsigned short* Qth = ws;
    unsigned short* Qtl = ws + plane;
    unsigned short* Kth = ws + 2 * plane;
    unsigned short* Ktl = ws + 3 * plane;
    unsigned short* Vh  = ws + 4 * plane;
    unsigned short* Vl  = ws + 5 * plane;
    float* Op = (float*)(ws + 6 * plane);              // 512*256*64 floats
    float* Mp = Op + (size_t)512 * 256 * 64;
    float* Lp = Mp + (size_t)512 * 64;

    const size_t need = 6 * plane * sizeof(unsigned short)
                      + ((size_t)512 * 256 * 64 + 2 * (size_t)512 * 64) * sizeof(float);
    const int split = (ws_size >= need) ? 1 : 0;  // ws_size fixed -> same path every call

    dim3 gp(NPIX / 64, CDIM / 64, 3 * BATCH);
    proj_kernel<<<gp, 256, 0, stream>>>(qf, kf, Wq, Wk, Wv, sq, bq, sk, bk, sv, bv,
                                        Qth, Qtl, Kth, Ktl, Vh, Vl);

    if (split) {
        flash_kernel<<<dim3(512), 512, 0, stream>>>(Qth, Qtl, Kth, Ktl, Vh, Vl,
                                                    Op, Mp, Lp, out, 1);
        merge_kernel<<<dim3(4096), 256, 0, stream>>>(Op, Mp, Lp, out);
    } else {
        flash_kernel<<<dim3(256), 512, 0, stream>>>(Qth, Qtl, Kth, Ktl, Vh, Vl,
                                                    Op, Mp, Lp, out, 0);
    }
}